// Round 20
// baseline (33.200 us; speedup 1.0000x reference)
//
#include <hip/hip_runtime.h>
#include <hip/hip_bf16.h>

// GRU cell: B=16384, IN=256, UNITS=256, K = IN+UNITS = 512.
//   z = sigmoid([h,x]@Wz + bz); r = sigmoid([h,x]@Wr + br)
//   h~ = tanh([r*h, x]@Ws + bs);  h' = (1-z)*h + z*h~
// Round 20: r19 + UN-DRAINED barriers. __syncthreads() emits
// s_waitcnt vmcnt(0) lgkmcnt(0) + s_barrier, draining every in-flight
// global prefetch at all 10 barriers. All our barriers only guard LDS,
// so use inline-asm "s_waitcnt lgkmcnt(0); s_barrier" instead — global
// loads (x regs, B-frag chains) stay in flight across barriers (T4).

#define ROWS 64

// barrier that waits only LDS ops, leaves global loads in flight
#define BAR_LDS() asm volatile("s_waitcnt lgkmcnt(0)\n\ts_barrier" ::: "memory")

typedef float f32x4 __attribute__((ext_vector_type(4)));
typedef __bf16 bf16x8 __attribute__((ext_vector_type(8)));
typedef unsigned short us8 __attribute__((ext_vector_type(8)));
typedef unsigned short us4v __attribute__((ext_vector_type(4)));
typedef unsigned short us2v __attribute__((ext_vector_type(2)));

static __device__ __forceinline__ unsigned short f2bf(float f) {
    __bf16 h = (__bf16)f;                              // RNE, enables v_cvt_pk
    return __builtin_bit_cast(unsigned short, h);
}
static __device__ __forceinline__ float bf2f(unsigned short u) {
    union { unsigned u; float f; } v; v.u = ((unsigned)u) << 16;
    return v.f;
}

// Pack W[512][256] (fp32 row-major) -> [kt][nt][lane][8] bf16 frags.
__global__ void pack_weights(const float* __restrict__ Wz,
                             const float* __restrict__ Wr,
                             const float* __restrict__ Ws,
                             unsigned short* __restrict__ out) {
    int gid = blockIdx.x * blockDim.x + threadIdx.x;   // 0 .. 49152
    int w    = gid >> 14;
    int rem  = gid & 16383;
    int kt   = rem >> 10;
    int rem2 = rem & 1023;
    int nt   = rem2 >> 6;
    int lane = rem2 & 63;
    int hi = lane >> 4, lo = lane & 15;
    const float* W = (w == 0) ? Wz : (w == 1) ? Wr : Ws;
    const float* src = W + (size_t)(kt * 32 + hi * 8) * 256 + nt * 16 + lo;
    us8 o;
#pragma unroll
    for (int j = 0; j < 8; ++j) o[j] = f2bf(src[(size_t)j * 256]);
    *(us8*)&out[(size_t)w * 131072 + (size_t)(((kt * 16 + nt) * 64 + lane) * 8)] = o;
}

__launch_bounds__(1024, 4)
__global__ void gru_main(const float* __restrict__ x,
                         const float* __restrict__ ph,
                         const float* __restrict__ bz,
                         const float* __restrict__ br,
                         const float* __restrict__ bs,
                         const unsigned short* __restrict__ Wp,
                         float* __restrict__ out) {
    __shared__ unsigned short sm[ROWS * 512];          // 64 KiB: [ph | x], swizzled
    __shared__ unsigned short rh[ROWS * 256];          // 32 KiB: r*ph, swizzled

    const int tid  = threadIdx.x;
    const int lane = tid & 63;
    const int wid  = tid >> 6;                         // 0..15 = N-slice (nt)
    const int brow = blockIdx.x * ROWS;

    const int l15 = lane & 15;
    const int kg  = (lane >> 4) << 3;                  // k sub-offset 0,8,16,24
    const int col = wid * 16 + l15;

    const unsigned short* pz = Wp          + (size_t)((wid * 64 + lane) * 8);
    const unsigned short* pr = Wp + 131072 + (size_t)((wid * 64 + lane) * 8);
    const unsigned short* ps = Wp + 262144 + (size_t)((wid * 64 + lane) * 8);
    // depth-2 z/r prefetch: kt=0 and kt=1 both fly during staging
    us8 b0n = *(const us8*)pz;
    us8 b1n = *(const us8*)pr;
    us8 b0a = *(const us8*)(pz + 8192);
    us8 b1a = *(const us8*)(pr + 8192);
    float bzc = bz[col], brc = br[col], bsc = bs[col];

    // ---- slice-pipelined ph staging interleaved with GEMM1a ----
    // slice j = k cols [j*32, j*32+32); thread: row=tid>>4, pair c2=(tid&15)*2.
    const int srow = tid >> 4;
    const int c2   = (tid & 15) << 1;
    const int sswr = (srow & 7) << 3;
    const float* phrow = ph + (size_t)(brow + srow) * 256 + c2;

    // x loads to regs: now genuinely fly under GEMM1a (barriers don't drain)
    float4 xr[4];
#pragma unroll
    for (int it = 0; it < 4; ++it) {
        int i   = tid + it * 1024;
        int row = i >> 6;
        int c4  = (i & 63) << 2;
        xr[it] = *(const float4*)&x[(size_t)(brow + row) * 256 + c4];
    }

    float2 sA = *(const float2*)(phrow + 0 * 32);      // 3 slice-loads in flight
    float2 sB = *(const float2*)(phrow + 1 * 32);
    float2 sC = *(const float2*)(phrow + 2 * 32);

    f32x4 accz[4] = {};
    f32x4 accr[4] = {};
#pragma unroll
    for (int j = 0; j < 8; ++j) {
        float2 sN;
        if (j + 3 < 8) sN = *(const float2*)(phrow + (j + 3) * 32);
        {   // ds_write slice j (waits only sA's load)
            us2v u; u.x = f2bf(sA.x); u.y = f2bf(sA.y);
            int scol = j * 32 + c2;
            *(us2v*)&sm[srow * 512 + (scol ^ sswr)] = u;
        }
        sA = sB; sB = sC; sC = sN;
        BAR_LDS();                                     // slice j visible; vmcnt flies

        // GEMM1a step kt=j (z,r), depth-2 B prefetch
        bf16x8 B0 = __builtin_bit_cast(bf16x8, b0n);
        bf16x8 B1 = __builtin_bit_cast(bf16x8, b1n);
        b0n = b0a; b1n = b1a;
        b0a = *(const us8*)(pz + (size_t)(j + 2) * 8192);   // j+2 <= 9 < 16
        b1a = *(const us8*)(pr + (size_t)(j + 2) * 8192);
        int ak = j * 32 + kg;
#pragma unroll
        for (int m = 0; m < 4; ++m) {
            int arow = m * 16 + l15;
            bf16x8 a = __builtin_bit_cast(bf16x8,
                *(const us8*)&sm[arow * 512 + (ak ^ ((arow & 7) << 3))]);
            accz[m] = __builtin_amdgcn_mfma_f32_16x16x32_bf16(a, B0, accz[m], 0, 0, 0);
            accr[m] = __builtin_amdgcn_mfma_f32_16x16x32_bf16(a, B1, accr[m], 0, 0, 0);
        }
    }

    // ---- write x (bf16) into k[256,512) ----
#pragma unroll
    for (int it = 0; it < 4; ++it) {
        int i   = tid + it * 1024;
        int row = i >> 6;
        int c4  = (i & 63) << 2;
        int swr = (row & 7) << 3;
        us4v v; v.x = f2bf(xr[it].x); v.y = f2bf(xr[it].y);
        v.z = f2bf(xr[it].z); v.w = f2bf(xr[it].w);
        *(us4v*)&sm[row * 512 + ((256 + c4) ^ swr)] = v;
    }
    BAR_LDS();                                         // x staged; vmcnt flies

    // prefetch Ws kt=8,9 (consumed inside fused GEMM1b)
    us8 s0n = *(const us8*)(ps + (size_t)8 * 8192);
    us8 s1n = *(const us8*)(ps + (size_t)9 * 8192);

    // ---- GEMM1b FUSED: z,r AND candidate-x over x half (kt 8..15) ----
    // z/r depth-2: entering with b0n=kt8 (loaded at j=6), b0a=kt9 (j=7).
    f32x4 accs[4] = {};
#pragma unroll 4
    for (int kt = 8; kt < 16; ++kt) {
        bf16x8 B0 = __builtin_bit_cast(bf16x8, b0n);
        bf16x8 B1 = __builtin_bit_cast(bf16x8, b1n);
        bf16x8 S  = __builtin_bit_cast(bf16x8, s0n);
        s0n = s1n;
        b0n = b0a; b1n = b1a;
        if (kt < 14) {
            size_t no = (size_t)(kt + 2) * 8192;
            b0a = *(const us8*)(pz + no);
            b1a = *(const us8*)(pr + no);
            s1n = *(const us8*)(ps + no);
        }
        int ak = kt * 32 + kg;
#pragma unroll
        for (int m = 0; m < 4; ++m) {
            int arow = m * 16 + l15;
            bf16x8 a = __builtin_bit_cast(bf16x8,
                *(const us8*)&sm[arow * 512 + (ak ^ ((arow & 7) << 3))]);
            accz[m] = __builtin_amdgcn_mfma_f32_16x16x32_bf16(a, B0, accz[m], 0, 0, 0);
            accr[m] = __builtin_amdgcn_mfma_f32_16x16x32_bf16(a, B1, accr[m], 0, 0, 0);
            accs[m] = __builtin_amdgcn_mfma_f32_16x16x32_bf16(a, S,  accs[m], 0, 0, 0);
        }
    }

    // prefetch Ws kt=0,1 now: latency hides under the sigmoid VALU phase
    s0n = *(const us8*)ps;
    s1n = *(const us8*)(ps + 8192);

    // ---- sigmoid; rh -> separate buffer; stash p,z ----
    float pst[4][4];
    const int rrow0 = (lane >> 4) * 4;
#pragma unroll
    for (int m = 0; m < 4; ++m) {
#pragma unroll
        for (int i = 0; i < 4; ++i) {
            int lrow = m * 16 + rrow0 + i;
            int cs = col ^ ((lrow & 7) << 3);
            float p = bf2f(sm[lrow * 512 + cs]);
            float z = 1.f / (1.f + __expf(-(accz[m][i] + bzc)));
            float r = 1.f / (1.f + __expf(-(accr[m][i] + brc)));
            accz[m][i] = z;
            pst[m][i]  = p;
            rh[lrow * 256 + cs] = f2bf(r * p);
        }
    }
    BAR_LDS();                                         // rh ready; Ws chain flies

    // ---- GEMM2-rh: kt 0..7 from rh, depth-2 Ws chain ----
#pragma unroll 4
    for (int kt = 0; kt < 8; ++kt) {
        bf16x8 B = __builtin_bit_cast(bf16x8, s0n);
        s0n = s1n;
        if (kt < 6) s1n = *(const us8*)(ps + (size_t)(kt + 2) * 8192);
        int ak = kt * 32 + kg;
#pragma unroll
        for (int m = 0; m < 4; ++m) {
            int arow = m * 16 + l15;
            bf16x8 a = __builtin_bit_cast(bf16x8,
                *(const us8*)&rh[arow * 256 + (ak ^ ((arow & 7) << 3))]);
            accs[m] = __builtin_amdgcn_mfma_f32_16x16x32_bf16(a, B, accs[m], 0, 0, 0);
        }
    }

    // ---- epilogue: h' = (1-z)*p + z*tanh(s+bs) ----
#pragma unroll
    for (int m = 0; m < 4; ++m) {
#pragma unroll
        for (int i = 0; i < 4; ++i) {
            float s = accs[m][i] + bsc;
            float e = __expf(-2.f * fabsf(s));
            float th = (1.f - e) / (1.f + e);
            th = (s < 0.f) ? -th : th;
            float z = accz[m][i];
            float p = pst[m][i];
            int grow = brow + m * 16 + rrow0 + i;
            out[(size_t)grow * 256 + col] = (1.f - z) * p + z * th;
        }
    }
}

extern "C" void kernel_launch(void* const* d_in, const int* in_sizes, int n_in,
                              void* d_out, int out_size, void* d_ws, size_t ws_size,
                              hipStream_t stream) {
    const float* x  = (const float*)d_in[0];
    const float* ph = (const float*)d_in[1];
    const float* Wz = (const float*)d_in[2];
    const float* bz = (const float*)d_in[3];
    const float* Wr = (const float*)d_in[4];
    const float* br = (const float*)d_in[5];
    const float* Ws = (const float*)d_in[6];
    const float* bs = (const float*)d_in[7];
    unsigned short* Wp = (unsigned short*)d_ws;        // 786432 bytes used

    hipLaunchKernelGGL(pack_weights, dim3(192), dim3(256), 0, stream, Wz, Wr, Ws, Wp);
    hipLaunchKernelGGL(gru_main, dim3(256), dim3(1024), 0, stream,
                       x, ph, bz, br, bs, Wp, (float*)d_out);
}

// Round 21
// 32.506 us; speedup vs baseline: 1.0214x; 1.0214x over previous
//
#include <hip/hip_runtime.h>
#include <hip/hip_bf16.h>

// GRU cell: B=16384, IN=256, UNITS=256, K = IN+UNITS = 512.
//   z = sigmoid([h,x]@Wz + bz); r = sigmoid([h,x]@Wr + br)
//   h~ = tanh([r*h, x]@Ws + bs);  h' = (1-z)*h + z*h~
// Round 21: gru_main = r19 verbatim (33.2us best) + nontemporal out stores.
// pack_weights split 2 threads/fragment (4 loads each, 384 blocks): halves
// the serial gather depth, doubles CU coverage -> attacks the ~3-5us
// pack+launch-gap component.

#define ROWS 64

typedef float f32x4 __attribute__((ext_vector_type(4)));
typedef __bf16 bf16x8 __attribute__((ext_vector_type(8)));
typedef unsigned short us8 __attribute__((ext_vector_type(8)));
typedef unsigned short us4v __attribute__((ext_vector_type(4)));
typedef unsigned short us2v __attribute__((ext_vector_type(2)));

static __device__ __forceinline__ unsigned short f2bf(float f) {
    __bf16 h = (__bf16)f;                              // RNE, enables v_cvt_pk
    return __builtin_bit_cast(unsigned short, h);
}
static __device__ __forceinline__ float bf2f(unsigned short u) {
    union { unsigned u; float f; } v; v.u = ((unsigned)u) << 16;
    return v.f;
}

// Pack W[512][256] (fp32 row-major) -> [kt][nt][lane][8] bf16 frags.
// 2 threads per fragment (half-frag each): 4 stride-256 loads + 8B store.
__global__ void pack_weights(const float* __restrict__ Wz,
                             const float* __restrict__ Wr,
                             const float* __restrict__ Ws,
                             unsigned short* __restrict__ out) {
    int gid = blockIdx.x * blockDim.x + threadIdx.x;   // 0 .. 98304
    int w    = gid >> 15;                              // 32768 half-frags per W
    int rem  = gid & 32767;
    int f    = rem >> 1;                               // fragment index
    int h    = rem & 1;                                // half: j0 = 4*h
    int kt   = f >> 10;
    int rem2 = f & 1023;
    int nt   = rem2 >> 6;
    int lane = rem2 & 63;
    int hi = lane >> 4, lo = lane & 15;
    const float* W = (w == 0) ? Wz : (w == 1) ? Wr : Ws;
    const float* src = W + (size_t)(kt * 32 + hi * 8 + h * 4) * 256 + nt * 16 + lo;
    us4v o;
#pragma unroll
    for (int j = 0; j < 4; ++j) o[j] = f2bf(src[(size_t)j * 256]);
    *(us4v*)&out[(size_t)w * 131072
                 + (size_t)(((kt * 16 + nt) * 64 + lane) * 8 + h * 4)] = o;
}

__launch_bounds__(1024, 4)
__global__ void gru_main(const float* __restrict__ x,
                         const float* __restrict__ ph,
                         const float* __restrict__ bz,
                         const float* __restrict__ br,
                         const float* __restrict__ bs,
                         const unsigned short* __restrict__ Wp,
                         float* __restrict__ out) {
    __shared__ unsigned short sm[ROWS * 512];          // 64 KiB: [ph | x], swizzled
    __shared__ unsigned short rh[ROWS * 256];          // 32 KiB: r*ph, swizzled

    const int tid  = threadIdx.x;
    const int lane = tid & 63;
    const int wid  = tid >> 6;                         // 0..15 = N-slice (nt)
    const int brow = blockIdx.x * ROWS;

    const int l15 = lane & 15;
    const int kg  = (lane >> 4) << 3;                  // k sub-offset 0,8,16,24
    const int col = wid * 16 + l15;

    const unsigned short* pz = Wp          + (size_t)((wid * 64 + lane) * 8);
    const unsigned short* pr = Wp + 131072 + (size_t)((wid * 64 + lane) * 8);
    const unsigned short* ps = Wp + 262144 + (size_t)((wid * 64 + lane) * 8);
    // depth-2 z/r prefetch: kt=0 and kt=1 both fly during staging
    us8 b0n = *(const us8*)pz;
    us8 b1n = *(const us8*)pr;
    us8 b0a = *(const us8*)(pz + 8192);
    us8 b1a = *(const us8*)(pr + 8192);
    float bzc = bz[col], brc = br[col], bsc = bs[col];

    // ---- slice-pipelined ph staging interleaved with GEMM1a ----
    // slice j = k cols [j*32, j*32+32); thread: row=tid>>4, pair c2=(tid&15)*2.
    const int srow = tid >> 4;
    const int c2   = (tid & 15) << 1;
    const int sswr = (srow & 7) << 3;
    const float* phrow = ph + (size_t)(brow + srow) * 256 + c2;

    // x loads to regs: fly under the GEMM1a pipeline
    float4 xr[4];
#pragma unroll
    for (int it = 0; it < 4; ++it) {
        int i   = tid + it * 1024;
        int row = i >> 6;
        int c4  = (i & 63) << 2;
        xr[it] = *(const float4*)&x[(size_t)(brow + row) * 256 + c4];
    }

    float2 sA = *(const float2*)(phrow + 0 * 32);      // 3 slice-loads in flight
    float2 sB = *(const float2*)(phrow + 1 * 32);
    float2 sC = *(const float2*)(phrow + 2 * 32);

    f32x4 accz[4] = {};
    f32x4 accr[4] = {};
#pragma unroll
    for (int j = 0; j < 8; ++j) {
        float2 sN;
        if (j + 3 < 8) sN = *(const float2*)(phrow + (j + 3) * 32);
        {   // ds_write slice j (waits only sA's load)
            us2v u; u.x = f2bf(sA.x); u.y = f2bf(sA.y);
            int scol = j * 32 + c2;
            *(us2v*)&sm[srow * 512 + (scol ^ sswr)] = u;
        }
        sA = sB; sB = sC; sC = sN;
        __syncthreads();                               // slice j visible

        // GEMM1a step kt=j (z,r), depth-2 B prefetch
        bf16x8 B0 = __builtin_bit_cast(bf16x8, b0n);
        bf16x8 B1 = __builtin_bit_cast(bf16x8, b1n);
        b0n = b0a; b1n = b1a;
        b0a = *(const us8*)(pz + (size_t)(j + 2) * 8192);   // j+2 <= 9 < 16
        b1a = *(const us8*)(pr + (size_t)(j + 2) * 8192);
        int ak = j * 32 + kg;
#pragma unroll
        for (int m = 0; m < 4; ++m) {
            int arow = m * 16 + l15;
            bf16x8 a = __builtin_bit_cast(bf16x8,
                *(const us8*)&sm[arow * 512 + (ak ^ ((arow & 7) << 3))]);
            accz[m] = __builtin_amdgcn_mfma_f32_16x16x32_bf16(a, B0, accz[m], 0, 0, 0);
            accr[m] = __builtin_amdgcn_mfma_f32_16x16x32_bf16(a, B1, accr[m], 0, 0, 0);
        }
    }

    // ---- write x (bf16) into k[256,512) ----
#pragma unroll
    for (int it = 0; it < 4; ++it) {
        int i   = tid + it * 1024;
        int row = i >> 6;
        int c4  = (i & 63) << 2;
        int swr = (row & 7) << 3;
        us4v v; v.x = f2bf(xr[it].x); v.y = f2bf(xr[it].y);
        v.z = f2bf(xr[it].z); v.w = f2bf(xr[it].w);
        *(us4v*)&sm[row * 512 + ((256 + c4) ^ swr)] = v;
    }
    __syncthreads();                                   // bar: x staged

    // prefetch Ws kt=8,9 (consumed inside fused GEMM1b)
    us8 s0n = *(const us8*)(ps + (size_t)8 * 8192);
    us8 s1n = *(const us8*)(ps + (size_t)9 * 8192);

    // ---- GEMM1b FUSED: z,r AND candidate-x over x half (kt 8..15) ----
    f32x4 accs[4] = {};
#pragma unroll 4
    for (int kt = 8; kt < 16; ++kt) {
        bf16x8 B0 = __builtin_bit_cast(bf16x8, b0n);
        bf16x8 B1 = __builtin_bit_cast(bf16x8, b1n);
        bf16x8 S  = __builtin_bit_cast(bf16x8, s0n);
        s0n = s1n;
        b0n = b0a; b1n = b1a;
        if (kt < 14) {
            size_t no = (size_t)(kt + 2) * 8192;
            b0a = *(const us8*)(pz + no);
            b1a = *(const us8*)(pr + no);
            s1n = *(const us8*)(ps + no);
        }
        int ak = kt * 32 + kg;
#pragma unroll
        for (int m = 0; m < 4; ++m) {
            int arow = m * 16 + l15;
            bf16x8 a = __builtin_bit_cast(bf16x8,
                *(const us8*)&sm[arow * 512 + (ak ^ ((arow & 7) << 3))]);
            accz[m] = __builtin_amdgcn_mfma_f32_16x16x32_bf16(a, B0, accz[m], 0, 0, 0);
            accr[m] = __builtin_amdgcn_mfma_f32_16x16x32_bf16(a, B1, accr[m], 0, 0, 0);
            accs[m] = __builtin_amdgcn_mfma_f32_16x16x32_bf16(a, S,  accs[m], 0, 0, 0);
        }
    }

    // prefetch Ws kt=0,1 now: latency hides under the sigmoid VALU phase
    s0n = *(const us8*)ps;
    s1n = *(const us8*)(ps + 8192);

    // ---- sigmoid; rh -> separate buffer; stash p,z ----
    float pst[4][4];
    const int rrow0 = (lane >> 4) * 4;
#pragma unroll
    for (int m = 0; m < 4; ++m) {
#pragma unroll
        for (int i = 0; i < 4; ++i) {
            int lrow = m * 16 + rrow0 + i;
            int cs = col ^ ((lrow & 7) << 3);
            float p = bf2f(sm[lrow * 512 + cs]);
            float z = 1.f / (1.f + __expf(-(accz[m][i] + bzc)));
            float r = 1.f / (1.f + __expf(-(accr[m][i] + brc)));
            accz[m][i] = z;
            pst[m][i]  = p;
            rh[lrow * 256 + cs] = f2bf(r * p);
        }
    }
    __syncthreads();                                   // rh ready

    // ---- GEMM2-rh: kt 0..7 from rh, depth-2 Ws chain ----
#pragma unroll 4
    for (int kt = 0; kt < 8; ++kt) {
        bf16x8 B = __builtin_bit_cast(bf16x8, s0n);
        s0n = s1n;
        if (kt < 6) s1n = *(const us8*)(ps + (size_t)(kt + 2) * 8192);
        int ak = kt * 32 + kg;
#pragma unroll
        for (int m = 0; m < 4; ++m) {
            int arow = m * 16 + l15;
            bf16x8 a = __builtin_bit_cast(bf16x8,
                *(const us8*)&rh[arow * 256 + (ak ^ ((arow & 7) << 3))]);
            accs[m] = __builtin_amdgcn_mfma_f32_16x16x32_bf16(a, B, accs[m], 0, 0, 0);
        }
    }

    // ---- epilogue: h' = (1-z)*p + z*tanh(s+bs); nontemporal stores ----
#pragma unroll
    for (int m = 0; m < 4; ++m) {
#pragma unroll
        for (int i = 0; i < 4; ++i) {
            float s = accs[m][i] + bsc;
            float e = __expf(-2.f * fabsf(s));
            float th = (1.f - e) / (1.f + e);
            th = (s < 0.f) ? -th : th;
            float z = accz[m][i];
            float p = pst[m][i];
            int grow = brow + m * 16 + rrow0 + i;
            __builtin_nontemporal_store((1.f - z) * p + z * th,
                                        &out[(size_t)grow * 256 + col]);
        }
    }
}

extern "C" void kernel_launch(void* const* d_in, const int* in_sizes, int n_in,
                              void* d_out, int out_size, void* d_ws, size_t ws_size,
                              hipStream_t stream) {
    const float* x  = (const float*)d_in[0];
    const float* ph = (const float*)d_in[1];
    const float* Wz = (const float*)d_in[2];
    const float* bz = (const float*)d_in[3];
    const float* Wr = (const float*)d_in[4];
    const float* br = (const float*)d_in[5];
    const float* Ws = (const float*)d_in[6];
    const float* bs = (const float*)d_in[7];
    unsigned short* Wp = (unsigned short*)d_ws;        // 786432 bytes used

    hipLaunchKernelGGL(pack_weights, dim3(384), dim3(256), 0, stream, Wz, Wr, Ws, Wp);
    hipLaunchKernelGGL(gru_main, dim3(256), dim3(1024), 0, stream,
                       x, ph, bz, br, bs, Wp, (float*)d_out);
}

// Round 23
// 31.886 us; speedup vs baseline: 1.0412x; 1.0194x over previous
//
#include <hip/hip_runtime.h>
#include <hip/hip_bf16.h>

// GRU cell: B=16384, IN=256, UNITS=256, K = IN+UNITS = 512.
//   z = sigmoid([h,x]@Wz + bz); r = sigmoid([h,x]@Wr + br)
//   h~ = tanh([r*h, x]@Ws + bs);  h' = (1-z)*h + z*h~
// Round 22 (resubmit after infra failure): r21 (best, 32.5us) with 64-col
// staging slices: 4 slices instead of 8 -> barrier count 11 -> 7. GEMM1a
// runs 2 kt per slice. Single-variable change vs r21.

#define ROWS 64

typedef float f32x4 __attribute__((ext_vector_type(4)));
typedef __bf16 bf16x8 __attribute__((ext_vector_type(8)));
typedef unsigned short us8 __attribute__((ext_vector_type(8)));
typedef unsigned short us4v __attribute__((ext_vector_type(4)));

static __device__ __forceinline__ unsigned short f2bf(float f) {
    __bf16 h = (__bf16)f;                              // RNE, enables v_cvt_pk
    return __builtin_bit_cast(unsigned short, h);
}
static __device__ __forceinline__ float bf2f(unsigned short u) {
    union { unsigned u; float f; } v; v.u = ((unsigned)u) << 16;
    return v.f;
}

// Pack W[512][256] (fp32 row-major) -> [kt][nt][lane][8] bf16 frags.
// 2 threads per fragment (half-frag each): 4 stride-256 loads + 8B store.
__global__ void pack_weights(const float* __restrict__ Wz,
                             const float* __restrict__ Wr,
                             const float* __restrict__ Ws,
                             unsigned short* __restrict__ out) {
    int gid = blockIdx.x * blockDim.x + threadIdx.x;   // 0 .. 98304
    int w    = gid >> 15;                              // 32768 half-frags per W
    int rem  = gid & 32767;
    int f    = rem >> 1;                               // fragment index
    int h    = rem & 1;                                // half: j0 = 4*h
    int kt   = f >> 10;
    int rem2 = f & 1023;
    int nt   = rem2 >> 6;
    int lane = rem2 & 63;
    int hi = lane >> 4, lo = lane & 15;
    const float* W = (w == 0) ? Wz : (w == 1) ? Wr : Ws;
    const float* src = W + (size_t)(kt * 32 + hi * 8 + h * 4) * 256 + nt * 16 + lo;
    us4v o;
#pragma unroll
    for (int j = 0; j < 4; ++j) o[j] = f2bf(src[(size_t)j * 256]);
    *(us4v*)&out[(size_t)w * 131072
                 + (size_t)(((kt * 16 + nt) * 64 + lane) * 8 + h * 4)] = o;
}

__launch_bounds__(1024, 4)
__global__ void gru_main(const float* __restrict__ x,
                         const float* __restrict__ ph,
                         const float* __restrict__ bz,
                         const float* __restrict__ br,
                         const float* __restrict__ bs,
                         const unsigned short* __restrict__ Wp,
                         float* __restrict__ out) {
    __shared__ unsigned short sm[ROWS * 512];          // 64 KiB: [ph | x], swizzled
    __shared__ unsigned short rh[ROWS * 256];          // 32 KiB: r*ph, swizzled

    const int tid  = threadIdx.x;
    const int lane = tid & 63;
    const int wid  = tid >> 6;                         // 0..15 = N-slice (nt)
    const int brow = blockIdx.x * ROWS;

    const int l15 = lane & 15;
    const int kg  = (lane >> 4) << 3;                  // k sub-offset 0,8,16,24
    const int col = wid * 16 + l15;

    const unsigned short* pz = Wp          + (size_t)((wid * 64 + lane) * 8);
    const unsigned short* pr = Wp + 131072 + (size_t)((wid * 64 + lane) * 8);
    const unsigned short* ps = Wp + 262144 + (size_t)((wid * 64 + lane) * 8);
    // depth-2 z/r prefetch: kt=0 and kt=1 both fly during staging
    us8 b0n = *(const us8*)pz;
    us8 b1n = *(const us8*)pr;
    us8 b0a = *(const us8*)(pz + 8192);
    us8 b1a = *(const us8*)(pr + 8192);
    float bzc = bz[col], brc = br[col], bsc = bs[col];

    // ---- slice-pipelined ph staging interleaved with GEMM1a ----
    // slice j = k cols [j*64, j*64+64); thread: row=tid>>4, c4=(tid&15)*4.
    const int srow = tid >> 4;
    const int c4s  = (tid & 15) << 2;
    const int sswr = (srow & 7) << 3;
    const float* phrow = ph + (size_t)(brow + srow) * 256 + c4s;

    // x loads to regs: fly under the GEMM1a pipeline
    float4 xr[4];
#pragma unroll
    for (int it = 0; it < 4; ++it) {
        int i   = tid + it * 1024;
        int row = i >> 6;
        int c4  = (i & 63) << 2;
        xr[it] = *(const float4*)&x[(size_t)(brow + row) * 256 + c4];
    }

    float4 sA = *(const float4*)(phrow + 0 * 64);      // 2 slice-loads in flight
    float4 sB = *(const float4*)(phrow + 1 * 64);

    f32x4 accz[4] = {};
    f32x4 accr[4] = {};
#pragma unroll
    for (int j = 0; j < 4; ++j) {                      // 4 slices of 64 cols
        float4 sN;
        if (j + 2 < 4) sN = *(const float4*)(phrow + (j + 2) * 64);
        {   // ds_write slice j (waits only sA's load)
            us4v u; u.x = f2bf(sA.x); u.y = f2bf(sA.y);
            u.z = f2bf(sA.z); u.w = f2bf(sA.w);
            int scol = j * 64 + c4s;
            *(us4v*)&sm[srow * 512 + (scol ^ sswr)] = u;
        }
        sA = sB; sB = sN;
        __syncthreads();                               // slice j visible

        // GEMM1a: 2 kt steps per slice (kt = 2j, 2j+1), depth-2 B prefetch
#pragma unroll
        for (int t = 0; t < 2; ++t) {
            int kt = j * 2 + t;
            bf16x8 B0 = __builtin_bit_cast(bf16x8, b0n);
            bf16x8 B1 = __builtin_bit_cast(bf16x8, b1n);
            b0n = b0a; b1n = b1a;
            b0a = *(const us8*)(pz + (size_t)(kt + 2) * 8192);  // kt+2 <= 9
            b1a = *(const us8*)(pr + (size_t)(kt + 2) * 8192);
            int ak = kt * 32 + kg;
#pragma unroll
            for (int m = 0; m < 4; ++m) {
                int arow = m * 16 + l15;
                bf16x8 a = __builtin_bit_cast(bf16x8,
                    *(const us8*)&sm[arow * 512 + (ak ^ ((arow & 7) << 3))]);
                accz[m] = __builtin_amdgcn_mfma_f32_16x16x32_bf16(a, B0, accz[m], 0, 0, 0);
                accr[m] = __builtin_amdgcn_mfma_f32_16x16x32_bf16(a, B1, accr[m], 0, 0, 0);
            }
        }
    }

    // ---- write x (bf16) into k[256,512) ----
#pragma unroll
    for (int it = 0; it < 4; ++it) {
        int i   = tid + it * 1024;
        int row = i >> 6;
        int c4  = (i & 63) << 2;
        int swr = (row & 7) << 3;
        us4v v; v.x = f2bf(xr[it].x); v.y = f2bf(xr[it].y);
        v.z = f2bf(xr[it].z); v.w = f2bf(xr[it].w);
        *(us4v*)&sm[row * 512 + ((256 + c4) ^ swr)] = v;
    }
    __syncthreads();                                   // bar: x staged

    // prefetch Ws kt=8,9 (consumed inside fused GEMM1b)
    us8 s0n = *(const us8*)(ps + (size_t)8 * 8192);
    us8 s1n = *(const us8*)(ps + (size_t)9 * 8192);

    // ---- GEMM1b FUSED: z,r AND candidate-x over x half (kt 8..15) ----
    f32x4 accs[4] = {};
#pragma unroll 4
    for (int kt = 8; kt < 16; ++kt) {
        bf16x8 B0 = __builtin_bit_cast(bf16x8, b0n);
        bf16x8 B1 = __builtin_bit_cast(bf16x8, b1n);
        bf16x8 S  = __builtin_bit_cast(bf16x8, s0n);
        s0n = s1n;
        b0n = b0a; b1n = b1a;
        if (kt < 14) {
            size_t no = (size_t)(kt + 2) * 8192;
            b0a = *(const us8*)(pz + no);
            b1a = *(const us8*)(pr + no);
            s1n = *(const us8*)(ps + no);
        }
        int ak = kt * 32 + kg;
#pragma unroll
        for (int m = 0; m < 4; ++m) {
            int arow = m * 16 + l15;
            bf16x8 a = __builtin_bit_cast(bf16x8,
                *(const us8*)&sm[arow * 512 + (ak ^ ((arow & 7) << 3))]);
            accz[m] = __builtin_amdgcn_mfma_f32_16x16x32_bf16(a, B0, accz[m], 0, 0, 0);
            accr[m] = __builtin_amdgcn_mfma_f32_16x16x32_bf16(a, B1, accr[m], 0, 0, 0);
            accs[m] = __builtin_amdgcn_mfma_f32_16x16x32_bf16(a, S,  accs[m], 0, 0, 0);
        }
    }

    // prefetch Ws kt=0,1 now: latency hides under the sigmoid VALU phase
    s0n = *(const us8*)ps;
    s1n = *(const us8*)(ps + 8192);

    // ---- sigmoid; rh -> separate buffer; stash p,z ----
    float pst[4][4];
    const int rrow0 = (lane >> 4) * 4;
#pragma unroll
    for (int m = 0; m < 4; ++m) {
#pragma unroll
        for (int i = 0; i < 4; ++i) {
            int lrow = m * 16 + rrow0 + i;
            int cs = col ^ ((lrow & 7) << 3);
            float p = bf2f(sm[lrow * 512 + cs]);
            float z = 1.f / (1.f + __expf(-(accz[m][i] + bzc)));
            float r = 1.f / (1.f + __expf(-(accr[m][i] + brc)));
            accz[m][i] = z;
            pst[m][i]  = p;
            rh[lrow * 256 + cs] = f2bf(r * p);
        }
    }
    __syncthreads();                                   // rh ready

    // ---- GEMM2-rh: kt 0..7 from rh, depth-2 Ws chain ----
#pragma unroll 4
    for (int kt = 0; kt < 8; ++kt) {
        bf16x8 B = __builtin_bit_cast(bf16x8, s0n);
        s0n = s1n;
        if (kt < 6) s1n = *(const us8*)(ps + (size_t)(kt + 2) * 8192);
        int ak = kt * 32 + kg;
#pragma unroll
        for (int m = 0; m < 4; ++m) {
            int arow = m * 16 + l15;
            bf16x8 a = __builtin_bit_cast(bf16x8,
                *(const us8*)&rh[arow * 256 + (ak ^ ((arow & 7) << 3))]);
            accs[m] = __builtin_amdgcn_mfma_f32_16x16x32_bf16(a, B, accs[m], 0, 0, 0);
        }
    }

    // ---- epilogue: h' = (1-z)*p + z*tanh(s+bs); nontemporal stores ----
#pragma unroll
    for (int m = 0; m < 4; ++m) {
#pragma unroll
        for (int i = 0; i < 4; ++i) {
            float s = accs[m][i] + bsc;
            float e = __expf(-2.f * fabsf(s));
            float th = (1.f - e) / (1.f + e);
            th = (s < 0.f) ? -th : th;
            float z = accz[m][i];
            float p = pst[m][i];
            int grow = brow + m * 16 + rrow0 + i;
            __builtin_nontemporal_store((1.f - z) * p + z * th,
                                        &out[(size_t)grow * 256 + col]);
        }
    }
}

extern "C" void kernel_launch(void* const* d_in, const int* in_sizes, int n_in,
                              void* d_out, int out_size, void* d_ws, size_t ws_size,
                              hipStream_t stream) {
    const float* x  = (const float*)d_in[0];
    const float* ph = (const float*)d_in[1];
    const float* Wz = (const float*)d_in[2];
    const float* bz = (const float*)d_in[3];
    const float* Wr = (const float*)d_in[4];
    const float* br = (const float*)d_in[5];
    const float* Ws = (const float*)d_in[6];
    const float* bs = (const float*)d_in[7];
    unsigned short* Wp = (unsigned short*)d_ws;        // 786432 bytes used

    hipLaunchKernelGGL(pack_weights, dim3(384), dim3(256), 0, stream, Wz, Wr, Ws, Wp);
    hipLaunchKernelGGL(gru_main, dim3(256), dim3(1024), 0, stream,
                       x, ph, bz, br, bs, Wp, (float*)d_out);
}